// Round 1
// baseline (289.023 us; speedup 1.0000x reference)
//
#include <hip/hip_runtime.h>

typedef short bf16x8 __attribute__((ext_vector_type(8)));
typedef float f32x4 __attribute__((ext_vector_type(4)));

#define AS1 __attribute__((address_space(1)))
#define AS3 __attribute__((address_space(3)))

__device__ __forceinline__ void gload16(const void* g, void* l) {
  __builtin_amdgcn_global_load_lds((const AS1 void*)g, (AS3 void*)l, 16, 0, 0);
}

__device__ __forceinline__ unsigned short f2bf(float f) {
  union { float f; unsigned u; } v; v.f = f;
  unsigned r = v.u + 0x7FFFu + ((v.u >> 16) & 1u);
  return (unsigned short)(r >> 16);
}

// ---------------- cast fp32 -> bf16, vectorized ----------------
__global__ __launch_bounds__(256) void cast_kernel(const float* __restrict__ in,
                                                   unsigned short* __restrict__ out, int n4) {
  int i = blockIdx.x * blockDim.x + threadIdx.x;
  if (i < n4) {
    float4 v = reinterpret_cast<const float4*>(in)[i];
    ushort4 o; o.x = f2bf(v.x); o.y = f2bf(v.y); o.z = f2bf(v.z); o.w = f2bf(v.w);
    reinterpret_cast<ushort4*>(out)[i] = o;
  }
}

// ---------------- 128x128 tile GEMM, C = A * B^T (both row-major, K-contig) ----------------
// MODE 0: QKV gemm -> writes bf16 qkv buffer (q,k cols) and transposed V into Vt
// MODE 1: proj gemm -> writes fp32 d_out with bias
template<int MODE>
__global__ __launch_bounds__(256) void gemm128(
    const unsigned short* __restrict__ A, const unsigned short* __restrict__ B,
    int K, int N,
    unsigned short* __restrict__ Cbf, unsigned short* __restrict__ Vt,
    float* __restrict__ Cf, const float* __restrict__ bias) {
  __shared__ unsigned short Ab[128 * 32];
  __shared__ unsigned short Bb[128 * 32];
  const int tid = threadIdx.x, lane = tid & 63, wave = tid >> 6;
  const int l15 = lane & 15, lhi = lane >> 4;
  const int m0 = blockIdx.y * 128, n0 = blockIdx.x * 128;
  const int wr = wave >> 1, wc = wave & 1;

  f32x4 acc[4][4] = {};

  const int rA = tid >> 2, ch = tid & 3;
  const unsigned short* aSrc = A + (size_t)(m0 + rA) * K + ch * 8;
  const unsigned short* bSrc = B + (size_t)(n0 + rA) * K + ch * 8;
  char* ldsA = (char*)Ab + wave * 1024;  // wave-uniform base; HW adds lane*16
  char* ldsB = (char*)Bb + wave * 1024;

  for (int k0 = 0; k0 < K; k0 += 32) {
    __syncthreads();
    gload16(aSrc + k0, ldsA);
    gload16(aSrc + (size_t)64 * K + k0, ldsA + 4096);
    gload16(bSrc + k0, ldsB);
    gload16(bSrc + (size_t)64 * K + k0, ldsB + 4096);
    __syncthreads();
    bf16x8 af[4], bfr[4];
#pragma unroll
    for (int mm = 0; mm < 4; ++mm)
      af[mm] = *reinterpret_cast<const bf16x8*>(&Ab[(wr * 64 + mm * 16 + l15) * 32 + lhi * 8]);
#pragma unroll
    for (int nn = 0; nn < 4; ++nn)
      bfr[nn] = *reinterpret_cast<const bf16x8*>(&Bb[(wc * 64 + nn * 16 + l15) * 32 + lhi * 8]);
#pragma unroll
    for (int mm = 0; mm < 4; ++mm)
#pragma unroll
      for (int nn = 0; nn < 4; ++nn)
        acc[mm][nn] = __builtin_amdgcn_mfma_f32_16x16x32_bf16(af[mm], bfr[nn], acc[mm][nn], 0, 0, 0);
  }

  if (MODE == 0) {
    const bool isV = (n0 >= 1536);
#pragma unroll
    for (int mm = 0; mm < 4; ++mm) {
      int gm = m0 + wr * 64 + mm * 16 + lhi * 4;
#pragma unroll
      for (int nn = 0; nn < 4; ++nn) {
        int gn = n0 + wc * 64 + nn * 16 + l15;
        if (!isV) {
#pragma unroll
          for (int r = 0; r < 4; ++r)
            Cbf[(size_t)(gm + r) * N + gn] = f2bf(acc[mm][nn][r]);
        } else {
          int d = gn & 63, hh = (gn >> 6) - 24;
          int bb = gm >> 10, nb = gm & 1023;
          ushort4 o;
          o.x = f2bf(acc[mm][nn][0]); o.y = f2bf(acc[mm][nn][1]);
          o.z = f2bf(acc[mm][nn][2]); o.w = f2bf(acc[mm][nn][3]);
          *reinterpret_cast<ushort4*>(&Vt[(size_t)((bb * 12 + hh) * 64 + d) * 1024 + nb]) = o;
        }
      }
    }
  } else {
#pragma unroll
    for (int mm = 0; mm < 4; ++mm) {
      int gm = m0 + wr * 64 + mm * 16 + lhi * 4;
#pragma unroll
      for (int nn = 0; nn < 4; ++nn) {
        int gn = n0 + wc * 64 + nn * 16 + l15;
        float bv = bias[gn];
#pragma unroll
        for (int r = 0; r < 4; ++r)
          Cf[(size_t)(gm + r) * N + gn] = acc[mm][nn][r] + bv;
      }
    }
  }
}

// ---------------- flash attention: 4 independent waves, 16 q-rows each ----------------
__global__ __launch_bounds__(256) void attn_kernel(
    const unsigned short* __restrict__ qkv, const unsigned short* __restrict__ vt,
    unsigned short* __restrict__ aout) {
  __shared__ unsigned short P[4][16 * 64];
  const int tid = threadIdx.x, lane = tid & 63, wave = tid >> 6;
  const int l15 = lane & 15, lhi = lane >> 4;
  const int bh = blockIdx.x >> 4, qt = blockIdx.x & 15;
  const int b = bh / 12, h = bh % 12;
  const float c1 = 0.125f * 1.44269504088896340736f;  // scale * log2(e)

  const int q0 = qt * 64 + wave * 16;
  const unsigned short* qptr = qkv + (size_t)(b * 1024 + q0 + l15) * 2304 + h * 64;
  bf16x8 qf0 = *reinterpret_cast<const bf16x8*>(qptr + lhi * 8);
  bf16x8 qf1 = *reinterpret_cast<const bf16x8*>(qptr + 32 + lhi * 8);

  const unsigned short* kbase = qkv + (size_t)(b * 1024) * 2304 + 768 + h * 64 + lhi * 8;
  const unsigned short* vbase = vt + (size_t)(bh * 64 + l15) * 1024 + lhi * 8;

  f32x4 oacc[4] = {};
  float mrun[4], lrun[4];
#pragma unroll
  for (int r = 0; r < 4; ++r) { mrun[r] = -1e30f; lrun[r] = 0.f; }

  unsigned short* pl = &P[wave][0];
  const int swz = ((l15 & 7) << 4);

  for (int kt = 0; kt < 16; ++kt) {
    const int kv0 = kt * 64;
    f32x4 s[4];
#pragma unroll
    for (int nt = 0; nt < 4; ++nt) {
      const unsigned short* kp = kbase + (size_t)(kv0 + nt * 16 + l15) * 2304;
      bf16x8 kf0 = *reinterpret_cast<const bf16x8*>(kp);
      bf16x8 kf1 = *reinterpret_cast<const bf16x8*>(kp + 32);
      f32x4 z = {};
      z = __builtin_amdgcn_mfma_f32_16x16x32_bf16(qf0, kf0, z, 0, 0, 0);
      z = __builtin_amdgcn_mfma_f32_16x16x32_bf16(qf1, kf1, z, 0, 0, 0);
      s[nt] = z;
    }
#pragma unroll
    for (int nt = 0; nt < 4; ++nt)
#pragma unroll
      for (int r = 0; r < 4; ++r) s[nt][r] *= c1;

    float rm[4];
#pragma unroll
    for (int r = 0; r < 4; ++r)
      rm[r] = fmaxf(fmaxf(s[0][r], s[1][r]), fmaxf(s[2][r], s[3][r]));
#pragma unroll
    for (int msk = 1; msk <= 8; msk <<= 1)
#pragma unroll
      for (int r = 0; r < 4; ++r) rm[r] = fmaxf(rm[r], __shfl_xor(rm[r], msk, 64));

    float alpha[4];
#pragma unroll
    for (int r = 0; r < 4; ++r) {
      float mn = fmaxf(mrun[r], rm[r]);
      alpha[r] = __builtin_amdgcn_exp2f(mrun[r] - mn);
      mrun[r] = mn;
    }
#pragma unroll
    for (int nt = 0; nt < 4; ++nt)
#pragma unroll
      for (int r = 0; r < 4; ++r) s[nt][r] = __builtin_amdgcn_exp2f(s[nt][r] - mrun[r]);

    float rs[4];
#pragma unroll
    for (int r = 0; r < 4; ++r) rs[r] = (s[0][r] + s[1][r]) + (s[2][r] + s[3][r]);
#pragma unroll
    for (int msk = 1; msk <= 8; msk <<= 1)
#pragma unroll
      for (int r = 0; r < 4; ++r) rs[r] += __shfl_xor(rs[r], msk, 64);
#pragma unroll
    for (int r = 0; r < 4; ++r) lrun[r] = lrun[r] * alpha[r] + rs[r];
#pragma unroll
    for (int dt = 0; dt < 4; ++dt)
#pragma unroll
      for (int r = 0; r < 4; ++r) oacc[dt][r] *= alpha[r];

    // P (acc layout) -> LDS bf16, XOR swizzle to make A-frag reads conflict-light
#pragma unroll
    for (int nt = 0; nt < 4; ++nt)
#pragma unroll
      for (int r = 0; r < 4; ++r) {
        int row = lhi * 4 + r;
        int byte = row * 128 + ((((nt * 16 + l15) * 2)) ^ ((row & 7) << 4));
        *reinterpret_cast<unsigned short*>((char*)pl + byte) = f2bf(s[nt][r]);
      }
    bf16x8 af0, af1;
    {
      int base = l15 * 128;
      af0 = *reinterpret_cast<const bf16x8*>((char*)pl + base + ((lhi * 16) ^ swz));
      af1 = *reinterpret_cast<const bf16x8*>((char*)pl + base + ((64 + lhi * 16) ^ swz));
    }
#pragma unroll
    for (int dt = 0; dt < 4; ++dt) {
      const unsigned short* vp = vbase + (size_t)(dt * 16) * 1024 + kv0;
      bf16x8 v0 = *reinterpret_cast<const bf16x8*>(vp);
      bf16x8 v1 = *reinterpret_cast<const bf16x8*>(vp + 32);
      oacc[dt] = __builtin_amdgcn_mfma_f32_16x16x32_bf16(af0, v0, oacc[dt], 0, 0, 0);
      oacc[dt] = __builtin_amdgcn_mfma_f32_16x16x32_bf16(af1, v1, oacc[dt], 0, 0, 0);
    }
  }

  float inv[4];
#pragma unroll
  for (int r = 0; r < 4; ++r) inv[r] = 1.f / lrun[r];
#pragma unroll
  for (int dt = 0; dt < 4; ++dt)
#pragma unroll
    for (int r = 0; r < 4; ++r) {
      int n = q0 + lhi * 4 + r;
      int d = dt * 16 + l15;
      aout[(size_t)(b * 1024 + n) * 768 + h * 64 + d] = f2bf(oacc[dt][r] * inv[r]);
    }
}

extern "C" void kernel_launch(void* const* d_in, const int* in_sizes, int n_in,
                              void* d_out, int out_size, void* d_ws, size_t ws_size,
                              hipStream_t stream) {
  const float* x      = (const float*)d_in[0];
  const float* qkv_w  = (const float*)d_in[1];
  const float* proj_w = (const float*)d_in[2];
  const float* proj_b = (const float*)d_in[3];
  float* out = (float*)d_out;

  char* ws = (char*)d_ws;
  unsigned short* xb     = (unsigned short*)(ws);                         // 8192x768 bf16
  unsigned short* wqkvb  = (unsigned short*)(ws + 12582912);              // 2304x768 bf16
  unsigned short* wprojb = (unsigned short*)(ws + 16121856);              // 768x768 bf16
  unsigned short* qkvb   = (unsigned short*)(ws + 17301504);              // 8192x2304 bf16
  unsigned short* vtb    = (unsigned short*)(ws + 55050240);              // 96x64x1024 bf16
  unsigned short* aob    = (unsigned short*)(ws + 67633152);              // 8192x768 bf16

  cast_kernel<<<6144, 256, 0, stream>>>(x, xb, 1572864);
  cast_kernel<<<1728, 256, 0, stream>>>(qkv_w, wqkvb, 442368);
  cast_kernel<<<576, 256, 0, stream>>>(proj_w, wprojb, 147456);

  dim3 g1(2304 / 128, 8192 / 128);
  gemm128<0><<<g1, 256, 0, stream>>>(xb, wqkvb, 768, 2304, qkvb, vtb, nullptr, nullptr);

  attn_kernel<<<96 * 16, 256, 0, stream>>>(qkvb, vtb, aob);

  dim3 g2(768 / 128, 8192 / 128);
  gemm128<1><<<g2, 256, 0, stream>>>(aob, wprojb, 768, 768, nullptr, nullptr, out, proj_b);
}

// Round 2
// 181.259 us; speedup vs baseline: 1.5945x; 1.5945x over previous
//
#include <hip/hip_runtime.h>

typedef short bf16x8 __attribute__((ext_vector_type(8)));
typedef float f32x4 __attribute__((ext_vector_type(4)));

#define AS1 __attribute__((address_space(1)))
#define AS3 __attribute__((address_space(3)))

__device__ __forceinline__ void gload16(const void* g, void* l) {
  __builtin_amdgcn_global_load_lds((const AS1 void*)g, (AS3 void*)l, 16, 0, 0);
}

__device__ __forceinline__ unsigned short f2bf(float f) {
  union { float f; unsigned u; } v; v.f = f;
  unsigned r = v.u + 0x7FFFu + ((v.u >> 16) & 1u);
  return (unsigned short)(r >> 16);
}

// ---------------- cast fp32 -> bf16, vectorized ----------------
__global__ __launch_bounds__(256) void cast_kernel(const float* __restrict__ in,
                                                   unsigned short* __restrict__ out, int n4) {
  int i = blockIdx.x * blockDim.x + threadIdx.x;
  if (i < n4) {
    float4 v = reinterpret_cast<const float4*>(in)[i];
    ushort4 o; o.x = f2bf(v.x); o.y = f2bf(v.y); o.z = f2bf(v.z); o.w = f2bf(v.w);
    reinterpret_cast<ushort4*>(out)[i] = o;
  }
}

// ---------------- 128x128 tile GEMM, C = A * B^T (both row-major, K-contig) ----------------
// MODE 0: QKV gemm -> head-packed Q [bh][n][64], K [bh][n][64], V^T [bh][64][n]
// MODE 1: proj gemm -> fp32 d_out with bias
template<int MODE>
__global__ __launch_bounds__(256) void gemm128(
    const unsigned short* __restrict__ A, const unsigned short* __restrict__ B,
    int K, int N,
    unsigned short* __restrict__ Qh, unsigned short* __restrict__ Kh,
    unsigned short* __restrict__ Vt,
    float* __restrict__ Cf, const float* __restrict__ bias) {
  __shared__ unsigned short Ab[128 * 32];
  __shared__ unsigned short Bb[128 * 32];
  const int tid = threadIdx.x, lane = tid & 63, wave = tid >> 6;
  const int l15 = lane & 15, lhi = lane >> 4;
  const int m0 = blockIdx.y * 128, n0 = blockIdx.x * 128;
  const int wr = wave >> 1, wc = wave & 1;

  f32x4 acc[4][4] = {};

  const int rA = tid >> 2, ch = tid & 3;
  const unsigned short* aSrc = A + (size_t)(m0 + rA) * K + ch * 8;
  const unsigned short* bSrc = B + (size_t)(n0 + rA) * K + ch * 8;
  char* ldsA = (char*)Ab + wave * 1024;
  char* ldsB = (char*)Bb + wave * 1024;

  for (int k0 = 0; k0 < K; k0 += 32) {
    __syncthreads();
    gload16(aSrc + k0, ldsA);
    gload16(aSrc + (size_t)64 * K + k0, ldsA + 4096);
    gload16(bSrc + k0, ldsB);
    gload16(bSrc + (size_t)64 * K + k0, ldsB + 4096);
    __syncthreads();
    bf16x8 af[4], bfr[4];
#pragma unroll
    for (int mm = 0; mm < 4; ++mm)
      af[mm] = *reinterpret_cast<const bf16x8*>(&Ab[(wr * 64 + mm * 16 + l15) * 32 + lhi * 8]);
#pragma unroll
    for (int nn = 0; nn < 4; ++nn)
      bfr[nn] = *reinterpret_cast<const bf16x8*>(&Bb[(wc * 64 + nn * 16 + l15) * 32 + lhi * 8]);
#pragma unroll
    for (int mm = 0; mm < 4; ++mm)
#pragma unroll
      for (int nn = 0; nn < 4; ++nn)
        acc[mm][nn] = __builtin_amdgcn_mfma_f32_16x16x32_bf16(af[mm], bfr[nn], acc[mm][nn], 0, 0, 0);
  }

  if (MODE == 0) {
    const int region = (n0 >= 1536) ? 2 : (n0 >= 768 ? 1 : 0);
#pragma unroll
    for (int mm = 0; mm < 4; ++mm) {
      int gm = m0 + wr * 64 + mm * 16 + lhi * 4;
      int bb = gm >> 10, nb = gm & 1023;
#pragma unroll
      for (int nn = 0; nn < 4; ++nn) {
        int gn = n0 + wc * 64 + nn * 16 + l15 - region * 768;
        int d = gn & 63, hh = gn >> 6;
        if (region == 2) {
          ushort4 o;
          o.x = f2bf(acc[mm][nn][0]); o.y = f2bf(acc[mm][nn][1]);
          o.z = f2bf(acc[mm][nn][2]); o.w = f2bf(acc[mm][nn][3]);
          *reinterpret_cast<ushort4*>(&Vt[((size_t)(bb * 12 + hh) * 64 + d) * 1024 + nb]) = o;
        } else {
          unsigned short* dst =
              (region == 0 ? Qh : Kh) + ((size_t)(bb * 12 + hh) * 1024 + nb) * 64 + d;
#pragma unroll
          for (int r = 0; r < 4; ++r) dst[(size_t)r * 64] = f2bf(acc[mm][nn][r]);
        }
      }
    }
  } else {
#pragma unroll
    for (int mm = 0; mm < 4; ++mm) {
      int gm = m0 + wr * 64 + mm * 16 + lhi * 4;
#pragma unroll
      for (int nn = 0; nn < 4; ++nn) {
        int gn = n0 + wc * 64 + nn * 16 + l15;
        float bv = bias[gn];
#pragma unroll
        for (int r = 0; r < 4; ++r)
          Cf[(size_t)(gm + r) * N + gn] = acc[mm][nn][r] + bv;
      }
    }
  }
}

// ---------------- flash attention: QBLK=128, KVBLK=64, LDS-staged K/V shared by 4 waves ----------------
__global__ __launch_bounds__(256) void attn_kernel(
    const unsigned short* __restrict__ qh, const unsigned short* __restrict__ kh,
    const unsigned short* __restrict__ vt, unsigned short* __restrict__ aout) {
  __shared__ unsigned short KT[2][4096];  // [kv 64][d 64] swizzled, 8KB/buf
  __shared__ unsigned short VT[2][4096];  // [d 64][kv 64] swizzled, 8KB/buf
  __shared__ unsigned short P[4][2048];   // per-wave 32x64 bf16

  const int tid = threadIdx.x, lane = tid & 63, wave = tid >> 6;
  const int l15 = lane & 15, lhi = lane >> 4;
  const int bh = blockIdx.x >> 3, qt = blockIdx.x & 7;
  const int b = bh / 12, h = bh % 12;
  const float c1 = 0.125f * 1.44269504088896340736f;  // scale * log2(e)

  // staging: thread t -> tile row = t>>3 (and +32), 16B chunk = t&7, inverse-swizzled src col
  const int srow = tid >> 3;
  const int scol = (((tid & 7) * 16) ^ ((srow & 7) << 4)) >> 1;  // element offset in row
  const unsigned short* kS0 = kh + ((size_t)bh * 1024 + srow) * 64 + scol;
  const unsigned short* kS1 = kS0 + (size_t)32 * 64;
  const unsigned short* vS0 = vt + ((size_t)bh * 64 + srow) * 1024 + scol;
  const unsigned short* vS1 = vS0 + (size_t)32 * 1024;
  char* kD = (char*)&KT[0][0] + wave * 1024;
  char* vD = (char*)&VT[0][0] + wave * 1024;

  // Q fragments: 32 rows per wave
  const int qw0 = qt * 128 + wave * 32;
  bf16x8 qf[2][2];
#pragma unroll
  for (int rb = 0; rb < 2; ++rb)
#pragma unroll
    for (int ks = 0; ks < 2; ++ks)
      qf[rb][ks] = *reinterpret_cast<const bf16x8*>(
          qh + ((size_t)bh * 1024 + qw0 + rb * 16 + l15) * 64 + ks * 32 + lhi * 8);

  f32x4 oacc[2][4] = {};
  float mrun[2][4], lrun[2][4];
#pragma unroll
  for (int rb = 0; rb < 2; ++rb)
#pragma unroll
    for (int r = 0; r < 4; ++r) { mrun[rb][r] = -1e30f; lrun[rb][r] = 0.f; }

  const int rswz = (l15 & 7) << 4;
  const int fo0 = l15 * 128 + ((lhi * 16) ^ rswz);
  const int fo1 = l15 * 128 + ((64 + lhi * 16) ^ rswz);
  unsigned short* pl = &P[wave][0];

  // prologue: stage tile 0 into buf 0
  gload16(kS0, kD); gload16(kS1, kD + 4096);
  gload16(vS0, vD); gload16(vS1, vD + 4096);

  for (int kt = 0; kt < 16; ++kt) {
    const int cur = kt & 1;
    if (kt < 15) {  // prefetch next tile into other buffer
      const int kv = (kt + 1) * 64;
      char* kd = kD + (cur ^ 1) * 8192;
      char* vd = vD + (cur ^ 1) * 8192;
      gload16(kS0 + (size_t)kv * 64, kd); gload16(kS1 + (size_t)kv * 64, kd + 4096);
      gload16(vS0 + kv, vd); gload16(vS1 + kv, vd + 4096);
      asm volatile("s_waitcnt vmcnt(4)" ::: "memory");  // cur tile landed; 4 prefetch in flight
    } else {
      asm volatile("s_waitcnt vmcnt(0)" ::: "memory");
    }
    __builtin_amdgcn_s_barrier();

    const char* kb = (const char*)&KT[cur][0];
    const char* vb = (const char*)&VT[cur][0];

    // QK^T: s[rb][nt], D[q=lhi*4+r][kv=l15] per 16x16 block
    f32x4 s[2][4] = {};
#pragma unroll
    for (int nt = 0; nt < 4; ++nt) {
      bf16x8 kf0 = *reinterpret_cast<const bf16x8*>(kb + nt * 2048 + fo0);
      bf16x8 kf1 = *reinterpret_cast<const bf16x8*>(kb + nt * 2048 + fo1);
#pragma unroll
      for (int rb = 0; rb < 2; ++rb) {
        s[rb][nt] = __builtin_amdgcn_mfma_f32_16x16x32_bf16(qf[rb][0], kf0, s[rb][nt], 0, 0, 0);
        s[rb][nt] = __builtin_amdgcn_mfma_f32_16x16x32_bf16(qf[rb][1], kf1, s[rb][nt], 0, 0, 0);
      }
    }

#pragma unroll
    for (int rb = 0; rb < 2; ++rb) {
#pragma unroll
      for (int nt = 0; nt < 4; ++nt)
#pragma unroll
        for (int r = 0; r < 4; ++r) s[rb][nt][r] *= c1;

      float rm[4];
#pragma unroll
      for (int r = 0; r < 4; ++r)
        rm[r] = fmaxf(fmaxf(s[rb][0][r], s[rb][1][r]), fmaxf(s[rb][2][r], s[rb][3][r]));
#pragma unroll
      for (int msk = 1; msk <= 8; msk <<= 1)
#pragma unroll
        for (int r = 0; r < 4; ++r) rm[r] = fmaxf(rm[r], __shfl_xor(rm[r], msk, 64));

      float alpha[4];
#pragma unroll
      for (int r = 0; r < 4; ++r) {
        float mn = fmaxf(mrun[rb][r], rm[r]);
        alpha[r] = __builtin_amdgcn_exp2f(mrun[rb][r] - mn);
        mrun[rb][r] = mn;
      }
#pragma unroll
      for (int nt = 0; nt < 4; ++nt)
#pragma unroll
        for (int r = 0; r < 4; ++r)
          s[rb][nt][r] = __builtin_amdgcn_exp2f(s[rb][nt][r] - mrun[rb][r]);

      float rs[4];
#pragma unroll
      for (int r = 0; r < 4; ++r)
        rs[r] = (s[rb][0][r] + s[rb][1][r]) + (s[rb][2][r] + s[rb][3][r]);
#pragma unroll
      for (int msk = 1; msk <= 8; msk <<= 1)
#pragma unroll
        for (int r = 0; r < 4; ++r) rs[r] += __shfl_xor(rs[r], msk, 64);
#pragma unroll
      for (int r = 0; r < 4; ++r) lrun[rb][r] = lrun[rb][r] * alpha[r] + rs[r];
#pragma unroll
      for (int dt = 0; dt < 4; ++dt)
#pragma unroll
        for (int r = 0; r < 4; ++r) oacc[rb][dt][r] *= alpha[r];

      // P (acc layout) -> swizzled LDS bf16
#pragma unroll
      for (int nt = 0; nt < 4; ++nt)
#pragma unroll
        for (int r = 0; r < 4; ++r) {
          int row = rb * 16 + lhi * 4 + r;
          int byte = row * 128 + ((((nt * 16 + l15) * 2)) ^ ((row & 7) << 4));
          *reinterpret_cast<unsigned short*>((char*)pl + byte) = f2bf(s[rb][nt][r]);
        }
    }

    bf16x8 paf[2][2];
#pragma unroll
    for (int rb = 0; rb < 2; ++rb) {
      paf[rb][0] = *reinterpret_cast<const bf16x8*>((char*)pl + rb * 2048 + fo0);
      paf[rb][1] = *reinterpret_cast<const bf16x8*>((char*)pl + rb * 2048 + fo1);
    }

#pragma unroll
    for (int dt = 0; dt < 4; ++dt) {
      bf16x8 vf0 = *reinterpret_cast<const bf16x8*>(vb + dt * 2048 + fo0);
      bf16x8 vf1 = *reinterpret_cast<const bf16x8*>(vb + dt * 2048 + fo1);
#pragma unroll
      for (int rb = 0; rb < 2; ++rb) {
        oacc[rb][dt] = __builtin_amdgcn_mfma_f32_16x16x32_bf16(paf[rb][0], vf0, oacc[rb][dt], 0, 0, 0);
        oacc[rb][dt] = __builtin_amdgcn_mfma_f32_16x16x32_bf16(paf[rb][1], vf1, oacc[rb][dt], 0, 0, 0);
      }
    }
    __builtin_amdgcn_s_barrier();
  }

#pragma unroll
  for (int rb = 0; rb < 2; ++rb) {
    float inv[4];
#pragma unroll
    for (int r = 0; r < 4; ++r) inv[r] = 1.f / lrun[rb][r];
#pragma unroll
    for (int dt = 0; dt < 4; ++dt)
#pragma unroll
      for (int r = 0; r < 4; ++r) {
        int n = qw0 + rb * 16 + lhi * 4 + r;
        int d = dt * 16 + l15;
        aout[((size_t)(b * 1024 + n)) * 768 + h * 64 + d] = f2bf(oacc[rb][dt][r] * inv[r]);
      }
  }
}

extern "C" void kernel_launch(void* const* d_in, const int* in_sizes, int n_in,
                              void* d_out, int out_size, void* d_ws, size_t ws_size,
                              hipStream_t stream) {
  const float* x      = (const float*)d_in[0];
  const float* qkv_w  = (const float*)d_in[1];
  const float* proj_w = (const float*)d_in[2];
  const float* proj_b = (const float*)d_in[3];
  float* out = (float*)d_out;

  char* ws = (char*)d_ws;
  unsigned short* xb     = (unsigned short*)(ws);              // 8192x768 bf16
  unsigned short* wqkvb  = (unsigned short*)(ws + 12582912);   // 2304x768
  unsigned short* wprojb = (unsigned short*)(ws + 16121856);   // 768x768
  unsigned short* qhb    = (unsigned short*)(ws + 17301504);   // [96][1024][64]
  unsigned short* khb    = (unsigned short*)(ws + 29884416);   // [96][1024][64]
  unsigned short* vtb    = (unsigned short*)(ws + 42467328);   // [96][64][1024]
  unsigned short* aob    = (unsigned short*)(ws + 55050240);   // 8192x768

  cast_kernel<<<6144, 256, 0, stream>>>(x, xb, 1572864);
  cast_kernel<<<1728, 256, 0, stream>>>(qkv_w, wqkvb, 442368);
  cast_kernel<<<576, 256, 0, stream>>>(proj_w, wprojb, 147456);

  dim3 g1(2304 / 128, 8192 / 128);
  gemm128<0><<<g1, 256, 0, stream>>>(xb, wqkvb, 768, 2304, qhb, khb, vtb, nullptr, nullptr);

  attn_kernel<<<96 * 8, 256, 0, stream>>>(qhb, khb, vtb, aob);

  dim3 g2(768 / 128, 8192 / 128);
  gemm128<1><<<g2, 256, 0, stream>>>(aob, wprojb, 768, 768, nullptr, nullptr, nullptr, out, proj_b);
}

// Round 6
// 150.944 us; speedup vs baseline: 1.9148x; 1.2008x over previous
//
#include <hip/hip_runtime.h>

typedef short bf16x8 __attribute__((ext_vector_type(8)));
typedef float f32x4 __attribute__((ext_vector_type(4)));

#define AS1 __attribute__((address_space(1)))
#define AS3 __attribute__((address_space(3)))

__device__ __forceinline__ void gload16(const void* g, void* l) {
  __builtin_amdgcn_global_load_lds((const AS1 void*)g, (AS3 void*)l, 16, 0, 0);
}

__device__ __forceinline__ unsigned short f2bf(float f) {
  union { float f; unsigned u; } v; v.f = f;
  unsigned r = v.u + 0x7FFFu + ((v.u >> 16) & 1u);
  return (unsigned short)(r >> 16);
}

__device__ __forceinline__ unsigned pack2(float a, float b) {
  return (unsigned)f2bf(a) | ((unsigned)f2bf(b) << 16);
}

// ---------------- cast fp32 -> bf16, vectorized ----------------
__global__ __launch_bounds__(256) void cast_kernel(const float* __restrict__ in,
                                                   unsigned short* __restrict__ out, int n4) {
  int i = blockIdx.x * blockDim.x + threadIdx.x;
  if (i < n4) {
    float4 v = reinterpret_cast<const float4*>(in)[i];
    ushort4 o; o.x = f2bf(v.x); o.y = f2bf(v.y); o.z = f2bf(v.z); o.w = f2bf(v.w);
    reinterpret_cast<ushort4*>(out)[i] = o;
  }
}

// ---------------- 128x128 tile GEMM, C = A * B^T (both row-major, K-contig) ----------------
template<int MODE>
__global__ __launch_bounds__(256) void gemm128(
    const unsigned short* __restrict__ A, const unsigned short* __restrict__ B,
    int K, int N,
    unsigned short* __restrict__ Qh, unsigned short* __restrict__ Kh,
    unsigned short* __restrict__ Vt,
    float* __restrict__ Cf, const float* __restrict__ bias) {
  __shared__ unsigned short Ab[128 * 32];
  __shared__ unsigned short Bb[128 * 32];
  const int tid = threadIdx.x, lane = tid & 63, wave = tid >> 6;
  const int l15 = lane & 15, lhi = lane >> 4;
  const int m0 = blockIdx.y * 128, n0 = blockIdx.x * 128;
  const int wr = wave >> 1, wc = wave & 1;

  f32x4 acc[4][4] = {};

  const int rA = tid >> 2, ch = tid & 3;
  const unsigned short* aSrc = A + (size_t)(m0 + rA) * K + ch * 8;
  const unsigned short* bSrc = B + (size_t)(n0 + rA) * K + ch * 8;
  char* ldsA = (char*)Ab + wave * 1024;
  char* ldsB = (char*)Bb + wave * 1024;

  for (int k0 = 0; k0 < K; k0 += 32) {
    __syncthreads();
    gload16(aSrc + k0, ldsA);
    gload16(aSrc + (size_t)64 * K + k0, ldsA + 4096);
    gload16(bSrc + k0, ldsB);
    gload16(bSrc + (size_t)64 * K + k0, ldsB + 4096);
    __syncthreads();
    bf16x8 af[4], bfr[4];
#pragma unroll
    for (int mm = 0; mm < 4; ++mm)
      af[mm] = *reinterpret_cast<const bf16x8*>(&Ab[(wr * 64 + mm * 16 + l15) * 32 + lhi * 8]);
#pragma unroll
    for (int nn = 0; nn < 4; ++nn)
      bfr[nn] = *reinterpret_cast<const bf16x8*>(&Bb[(wc * 64 + nn * 16 + l15) * 32 + lhi * 8]);
#pragma unroll
    for (int mm = 0; mm < 4; ++mm)
#pragma unroll
      for (int nn = 0; nn < 4; ++nn)
        acc[mm][nn] = __builtin_amdgcn_mfma_f32_16x16x32_bf16(af[mm], bfr[nn], acc[mm][nn], 0, 0, 0);
  }

  if (MODE == 0) {
    const int region = (n0 >= 1536) ? 2 : (n0 >= 768 ? 1 : 0);
#pragma unroll
    for (int mm = 0; mm < 4; ++mm) {
      int gm = m0 + wr * 64 + mm * 16 + lhi * 4;
      int bb = gm >> 10, nb = gm & 1023;
#pragma unroll
      for (int nn = 0; nn < 4; ++nn) {
        int gn = n0 + wc * 64 + nn * 16 + l15 - region * 768;
        int d = gn & 63, hh = gn >> 6;
        if (region == 2) {
          ushort4 o;
          o.x = f2bf(acc[mm][nn][0]); o.y = f2bf(acc[mm][nn][1]);
          o.z = f2bf(acc[mm][nn][2]); o.w = f2bf(acc[mm][nn][3]);
          *reinterpret_cast<ushort4*>(&Vt[((size_t)(bb * 12 + hh) * 64 + d) * 1024 + nb]) = o;
        } else {
          unsigned short* dst =
              (region == 0 ? Qh : Kh) + ((size_t)(bb * 12 + hh) * 1024 + nb) * 64 + d;
#pragma unroll
          for (int r = 0; r < 4; ++r) dst[(size_t)r * 64] = f2bf(acc[mm][nn][r]);
        }
      }
    }
  } else {
#pragma unroll
    for (int mm = 0; mm < 4; ++mm) {
      int gm = m0 + wr * 64 + mm * 16 + lhi * 4;
#pragma unroll
      for (int nn = 0; nn < 4; ++nn) {
        int gn = n0 + wc * 64 + nn * 16 + l15;
        float bv = bias[gn];
#pragma unroll
        for (int r = 0; r < 4; ++r)
          Cf[(size_t)(gm + r) * N + gn] = acc[mm][nn][r] + bv;
      }
    }
  }
}

// ---------------- flash attention: QBLK=128, KVBLK=64, LDS-staged K/V, swapped QK^T ----------------
// QK^T = mfma(K, Q): D[kv][q], col=q=l15 per-lane -> kv-reduce = local tree + 2 shuffles.
// PV identical to the verified round-2 path: A=P (from LDS, swizzled), B=V (from LDS).
__global__ __launch_bounds__(256) void attn_kernel(
    const unsigned short* __restrict__ qh, const unsigned short* __restrict__ kh,
    const unsigned short* __restrict__ vt, unsigned short* __restrict__ aout) {
  __shared__ unsigned short KT[2][4096];  // [kv 64][d 64] swizzled, 8KB/buf
  __shared__ unsigned short VT[2][4096];  // [d 64][kv 64] swizzled, 8KB/buf
  __shared__ unsigned short P[4][2048];   // per-wave 32x64 bf16
  __shared__ float Al[4][32];             // per-wave alpha[q] (rescale)
  __shared__ float Li[4][32];             // per-wave lrun[q] (final norm)

  const int tid = threadIdx.x, lane = tid & 63, wave = tid >> 6;
  const int l15 = lane & 15, lhi = lane >> 4;
  const int bh = blockIdx.x >> 3, qt = blockIdx.x & 7;
  const int b = bh / 12, h = bh % 12;
  const float c1 = 0.125f * 1.44269504088896340736f;  // scale * log2(e)

  // staging: thread t -> tile row = t>>3 (and +32), 16B chunk = t&7, inverse-swizzled src col
  const int srow = tid >> 3;
  const int scol = (((tid & 7) * 16) ^ ((srow & 7) << 4)) >> 1;
  const unsigned short* kS0 = kh + ((size_t)bh * 1024 + srow) * 64 + scol;
  const unsigned short* kS1 = kS0 + (size_t)32 * 64;
  const unsigned short* vS0 = vt + ((size_t)bh * 64 + srow) * 1024 + scol;
  const unsigned short* vS1 = vS0 + (size_t)32 * 1024;
  char* kD = (char*)&KT[0][0] + wave * 1024;
  char* vD = (char*)&VT[0][0] + wave * 1024;

  // Q fragments: 32 rows per wave (q = q0w + rb*16 + l15, d = ks*32 + lhi*8 + j)
  const int qw0 = qt * 128 + wave * 32;
  bf16x8 qf[2][2];
#pragma unroll
  for (int rb = 0; rb < 2; ++rb)
#pragma unroll
    for (int ks = 0; ks < 2; ++ks)
      qf[rb][ks] = *reinterpret_cast<const bf16x8*>(
          qh + ((size_t)bh * 1024 + qw0 + rb * 16 + l15) * 64 + ks * 32 + lhi * 8);

  f32x4 oacc[2][4] = {};
  float mrun[2] = {-1e30f, -1e30f}, lrun[2] = {0.f, 0.f};

  const int rswz = (l15 & 7) << 4;
  const int fo0 = l15 * 128 + ((lhi * 16) ^ rswz);
  const int fo1 = l15 * 128 + ((64 + lhi * 16) ^ rswz);
  unsigned short* pl = &P[wave][0];

  // prologue: stage tile 0 into buf 0
  gload16(kS0, kD); gload16(kS1, kD + 4096);
  gload16(vS0, vD); gload16(vS1, vD + 4096);

  for (int kt = 0; kt < 16; ++kt) {
    const int cur = kt & 1;
    if (kt < 15) {  // prefetch next tile into other buffer
      const int kv = (kt + 1) * 64;
      char* kd = kD + (cur ^ 1) * 8192;
      char* vd = vD + (cur ^ 1) * 8192;
      gload16(kS0 + (size_t)kv * 64, kd); gload16(kS1 + (size_t)kv * 64, kd + 4096);
      gload16(vS0 + kv, vd); gload16(vS1 + kv, vd + 4096);
      asm volatile("s_waitcnt vmcnt(4)" ::: "memory");
    } else {
      asm volatile("s_waitcnt vmcnt(0)" ::: "memory");
    }
    __builtin_amdgcn_s_barrier();

    const char* kb = (const char*)&KT[cur][0];
    const char* vb = (const char*)&VT[cur][0];

    // QK^T swapped: s[rb][nt] = D[kv = nt*16 + lhi*4 + r][q = rb*16 + l15]
    f32x4 s[2][4] = {};
#pragma unroll
    for (int nt = 0; nt < 4; ++nt) {
      bf16x8 kf0 = *reinterpret_cast<const bf16x8*>(kb + nt * 2048 + fo0);
      bf16x8 kf1 = *reinterpret_cast<const bf16x8*>(kb + nt * 2048 + fo1);
#pragma unroll
      for (int rb = 0; rb < 2; ++rb) {
        s[rb][nt] = __builtin_amdgcn_mfma_f32_16x16x32_bf16(kf0, qf[rb][0], s[rb][nt], 0, 0, 0);
        s[rb][nt] = __builtin_amdgcn_mfma_f32_16x16x32_bf16(kf1, qf[rb][1], s[rb][nt], 0, 0, 0);
      }
    }

    // ---- softmax: per-lane column q -> local tree + 2 shuffles ----
    float mt[2];
#pragma unroll
    for (int rb = 0; rb < 2; ++rb) {
      float a0 = fmaxf(fmaxf(s[rb][0][0], s[rb][0][1]), fmaxf(s[rb][0][2], s[rb][0][3]));
      float a1 = fmaxf(fmaxf(s[rb][1][0], s[rb][1][1]), fmaxf(s[rb][1][2], s[rb][1][3]));
      float a2 = fmaxf(fmaxf(s[rb][2][0], s[rb][2][1]), fmaxf(s[rb][2][2], s[rb][2][3]));
      float a3 = fmaxf(fmaxf(s[rb][3][0], s[rb][3][1]), fmaxf(s[rb][3][2], s[rb][3][3]));
      float rm = fmaxf(fmaxf(a0, a1), fmaxf(a2, a3));
      rm = fmaxf(rm, __shfl_xor(rm, 16, 64));
      rm = fmaxf(rm, __shfl_xor(rm, 32, 64));
      mt[rb] = rm * c1;
    }

    // T13 defer-max: rescale only when some q's max grew by >8 (log2 domain)
    bool ok = (mt[0] - mrun[0] <= 8.f) && (mt[1] - mrun[1] <= 8.f);
    if (!__all(ok)) {
      float al[2];
#pragma unroll
      for (int rb = 0; rb < 2; ++rb) {
        float mn = fmaxf(mrun[rb], mt[rb]);
        al[rb] = __builtin_amdgcn_exp2f(mrun[rb] - mn);
        mrun[rb] = mn;
        lrun[rb] *= al[rb];
      }
      if (lhi == 0) { Al[wave][l15] = al[0]; Al[wave][16 + l15] = al[1]; }
#pragma unroll
      for (int rb = 0; rb < 2; ++rb) {
        f32x4 av = *reinterpret_cast<const f32x4*>(&Al[wave][rb * 16 + lhi * 4]);
#pragma unroll
        for (int dt = 0; dt < 4; ++dt)
#pragma unroll
          for (int r = 0; r < 4; ++r) oacc[rb][dt][r] *= av[r];
      }
    }

#pragma unroll
    for (int rb = 0; rb < 2; ++rb) {
#pragma unroll
      for (int nt = 0; nt < 4; ++nt)
#pragma unroll
        for (int r = 0; r < 4; ++r)
          s[rb][nt][r] = __builtin_amdgcn_exp2f(__builtin_fmaf(s[rb][nt][r], c1, -mrun[rb]));

      float b0 = (s[rb][0][0] + s[rb][0][1]) + (s[rb][0][2] + s[rb][0][3]);
      float b1 = (s[rb][1][0] + s[rb][1][1]) + (s[rb][1][2] + s[rb][1][3]);
      float b2 = (s[rb][2][0] + s[rb][2][1]) + (s[rb][2][2] + s[rb][2][3]);
      float b3 = (s[rb][3][0] + s[rb][3][1]) + (s[rb][3][2] + s[rb][3][3]);
      float rs = (b0 + b1) + (b2 + b3);
      rs += __shfl_xor(rs, 16, 64);
      rs += __shfl_xor(rs, 32, 64);
      lrun[rb] += rs;
    }

    // ---- P -> swizzled LDS, packed b64 writes ----
    // lane holds kv = nt*16 + lhi*4 + (0..3) for row q = rb*16 + l15
#pragma unroll
    for (int rb = 0; rb < 2; ++rb)
#pragma unroll
      for (int nt = 0; nt < 4; ++nt) {
        uint2 wv;
        wv.x = pack2(s[rb][nt][0], s[rb][nt][1]);
        wv.y = pack2(s[rb][nt][2], s[rb][nt][3]);
        *reinterpret_cast<uint2*>(
            (char*)pl + rb * 2048 + l15 * 128 + ((nt * 32 + lhi * 8) ^ rswz)) = wv;
      }

    bf16x8 paf[2][2];
#pragma unroll
    for (int rb = 0; rb < 2; ++rb) {
      paf[rb][0] = *reinterpret_cast<const bf16x8*>((char*)pl + rb * 2048 + fo0);
      paf[rb][1] = *reinterpret_cast<const bf16x8*>((char*)pl + rb * 2048 + fo1);
    }

#pragma unroll
    for (int dt = 0; dt < 4; ++dt) {
      bf16x8 vf0 = *reinterpret_cast<const bf16x8*>(vb + dt * 2048 + fo0);
      bf16x8 vf1 = *reinterpret_cast<const bf16x8*>(vb + dt * 2048 + fo1);
#pragma unroll
      for (int rb = 0; rb < 2; ++rb) {
        oacc[rb][dt] = __builtin_amdgcn_mfma_f32_16x16x32_bf16(paf[rb][0], vf0, oacc[rb][dt], 0, 0, 0);
        oacc[rb][dt] = __builtin_amdgcn_mfma_f32_16x16x32_bf16(paf[rb][1], vf1, oacc[rb][dt], 0, 0, 0);
      }
    }
    __builtin_amdgcn_s_barrier();
  }

  // ---- final normalize: redistribute lrun (per q=l15) to oacc rows (q=lhi*4+r) ----
  if (lhi == 0) { Li[wave][l15] = lrun[0]; Li[wave][16 + l15] = lrun[1]; }
#pragma unroll
  for (int rb = 0; rb < 2; ++rb) {
    f32x4 lv = *reinterpret_cast<const f32x4*>(&Li[wave][rb * 16 + lhi * 4]);
    float inv[4];
#pragma unroll
    for (int r = 0; r < 4; ++r) inv[r] = 1.f / lv[r];
#pragma unroll
    for (int dt = 0; dt < 4; ++dt)
#pragma unroll
      for (int r = 0; r < 4; ++r) {
        int n = qw0 + rb * 16 + lhi * 4 + r;
        int d = dt * 16 + l15;
        aout[((size_t)(b * 1024 + n)) * 768 + h * 64 + d] = f2bf(oacc[rb][dt][r] * inv[r]);
      }
  }
}

extern "C" void kernel_launch(void* const* d_in, const int* in_sizes, int n_in,
                              void* d_out, int out_size, void* d_ws, size_t ws_size,
                              hipStream_t stream) {
  const float* x      = (const float*)d_in[0];
  const float* qkv_w  = (const float*)d_in[1];
  const float* proj_w = (const float*)d_in[2];
  const float* proj_b = (const float*)d_in[3];
  float* out = (float*)d_out;

  char* ws = (char*)d_ws;
  unsigned short* xb     = (unsigned short*)(ws);              // 8192x768 bf16
  unsigned short* wqkvb  = (unsigned short*)(ws + 12582912);   // 2304x768
  unsigned short* wprojb = (unsigned short*)(ws + 16121856);   // 768x768
  unsigned short* qhb    = (unsigned short*)(ws + 17301504);   // [96][1024][64]
  unsigned short* khb    = (unsigned short*)(ws + 29884416);   // [96][1024][64]
  unsigned short* vtb    = (unsigned short*)(ws + 42467328);   // [96][64][1024]
  unsigned short* aob    = (unsigned short*)(ws + 55050240);   // 8192x768

  cast_kernel<<<6144, 256, 0, stream>>>(x, xb, 1572864);
  cast_kernel<<<1728, 256, 0, stream>>>(qkv_w, wqkvb, 442368);
  cast_kernel<<<576, 256, 0, stream>>>(proj_w, wprojb, 147456);

  dim3 g1(2304 / 128, 8192 / 128);
  gemm128<0><<<g1, 256, 0, stream>>>(xb, wqkvb, 768, 2304, qhb, khb, vtb, nullptr, nullptr);

  attn_kernel<<<96 * 8, 256, 0, stream>>>(qhb, khb, vtb, aob);

  dim3 g2(768 / 128, 8192 / 128);
  gemm128<1><<<g2, 256, 0, stream>>>(aob, wprojb, 768, 768, nullptr, nullptr, nullptr, out, proj_b);
}

// Round 7
// 132.465 us; speedup vs baseline: 2.1819x; 1.1395x over previous
//
#include <hip/hip_runtime.h>

typedef short bf16x8 __attribute__((ext_vector_type(8)));
typedef float f32x4 __attribute__((ext_vector_type(4)));

#define AS1 __attribute__((address_space(1)))
#define AS3 __attribute__((address_space(3)))

__device__ __forceinline__ void gload16(const void* g, void* l) {
  __builtin_amdgcn_global_load_lds((const AS1 void*)g, (AS3 void*)l, 16, 0, 0);
}

__device__ __forceinline__ unsigned short f2bf(float f) {
  union { float f; unsigned u; } v; v.f = f;
  unsigned r = v.u + 0x7FFFu + ((v.u >> 16) & 1u);
  return (unsigned short)(r >> 16);
}

// packed f32x2 -> bf16x2 (low = a, high = b), RNE — same rounding as f2bf
__device__ __forceinline__ unsigned cvtpk(float a, float b) {
  unsigned r;
  asm("v_cvt_pk_bf16_f32 %0, %1, %2" : "=v"(r) : "v"(a), "v"(b));
  return r;
}

// ---------------- cast fp32 -> bf16, vectorized ----------------
__global__ __launch_bounds__(256) void cast_kernel(const float* __restrict__ in,
                                                   unsigned short* __restrict__ out, int n4) {
  int i = blockIdx.x * blockDim.x + threadIdx.x;
  if (i < n4) {
    float4 v = reinterpret_cast<const float4*>(in)[i];
    ushort4 o; o.x = f2bf(v.x); o.y = f2bf(v.y); o.z = f2bf(v.z); o.w = f2bf(v.w);
    reinterpret_cast<ushort4*>(out)[i] = o;
  }
}

// ---------------- 128x128 tile GEMM, BK=64, swizzled LDS, C = A * B^T ----------------
// LDS [128 rows][64 cols] bf16, 128B rows; LDS[row][c] = G[row][c ^ ((row&7)<<4)] (byte-space).
// MODE 0: QKV gemm -> head-packed Q [bh][n][64], K [bh][n][64], V^T [bh][64][n]
// MODE 1: proj gemm -> fp32 d_out with bias
template<int MODE>
__global__ __launch_bounds__(256) void gemm128(
    const unsigned short* __restrict__ A, const unsigned short* __restrict__ B,
    int K, int N,
    unsigned short* __restrict__ Qh, unsigned short* __restrict__ Kh,
    unsigned short* __restrict__ Vt,
    float* __restrict__ Cf, const float* __restrict__ bias) {
  __shared__ unsigned short Ab[128 * 64];  // 16 KB
  __shared__ unsigned short Bb[128 * 64];  // 16 KB
  const int tid = threadIdx.x, lane = tid & 63, wave = tid >> 6;
  const int l15 = lane & 15, lhi = lane >> 4;
  const int m0 = blockIdx.y * 128, n0 = blockIdx.x * 128;
  const int wr = wave >> 1, wc = wave & 1;

  f32x4 acc[4][4] = {};

  // staging: thread t -> row = t>>3 (+32i), 16B chunk = t&7, inverse-swizzled source col
  const int srow = tid >> 3;
  const int scol = (((tid & 7) * 16) ^ ((srow & 7) << 4)) >> 1;  // elements
  const unsigned short* aSrc = A + (size_t)(m0 + srow) * K + scol;
  const unsigned short* bSrc = B + (size_t)(n0 + srow) * K + scol;
  char* ldsA = (char*)Ab + wave * 1024;
  char* ldsB = (char*)Bb + wave * 1024;

  const int rswz = (l15 & 7) << 4;

  for (int k0 = 0; k0 < K; k0 += 64) {
    __syncthreads();
#pragma unroll
    for (int i = 0; i < 4; ++i) {
      gload16(aSrc + k0 + (size_t)32 * K * i, ldsA + i * 4096);
      gload16(bSrc + k0 + (size_t)32 * K * i, ldsB + i * 4096);
    }
    __syncthreads();
#pragma unroll
    for (int ks = 0; ks < 2; ++ks) {
      bf16x8 af[4], bfr[4];
#pragma unroll
      for (int mm = 0; mm < 4; ++mm)
        af[mm] = *reinterpret_cast<const bf16x8*>(
            (char*)Ab + (wr * 64 + mm * 16 + l15) * 128 + ((ks * 64 + lhi * 16) ^ rswz));
#pragma unroll
      for (int nn = 0; nn < 4; ++nn)
        bfr[nn] = *reinterpret_cast<const bf16x8*>(
            (char*)Bb + (wc * 64 + nn * 16 + l15) * 128 + ((ks * 64 + lhi * 16) ^ rswz));
#pragma unroll
      for (int mm = 0; mm < 4; ++mm)
#pragma unroll
        for (int nn = 0; nn < 4; ++nn)
          acc[mm][nn] = __builtin_amdgcn_mfma_f32_16x16x32_bf16(af[mm], bfr[nn], acc[mm][nn], 0, 0, 0);
    }
  }

  if (MODE == 0) {
    const int region = (n0 >= 1536) ? 2 : (n0 >= 768 ? 1 : 0);
#pragma unroll
    for (int mm = 0; mm < 4; ++mm) {
      int gm = m0 + wr * 64 + mm * 16 + lhi * 4;
      int bb = gm >> 10, nb = gm & 1023;
#pragma unroll
      for (int nn = 0; nn < 4; ++nn) {
        int gn = n0 + wc * 64 + nn * 16 + l15 - region * 768;
        int d = gn & 63, hh = gn >> 6;
        if (region == 2) {
          ushort4 o;
          o.x = f2bf(acc[mm][nn][0]); o.y = f2bf(acc[mm][nn][1]);
          o.z = f2bf(acc[mm][nn][2]); o.w = f2bf(acc[mm][nn][3]);
          *reinterpret_cast<ushort4*>(&Vt[((size_t)(bb * 12 + hh) * 64 + d) * 1024 + nb]) = o;
        } else {
          unsigned short* dst =
              (region == 0 ? Qh : Kh) + ((size_t)(bb * 12 + hh) * 1024 + nb) * 64 + d;
#pragma unroll
          for (int r = 0; r < 4; ++r) dst[(size_t)r * 64] = f2bf(acc[mm][nn][r]);
        }
      }
    }
  } else {
#pragma unroll
    for (int mm = 0; mm < 4; ++mm) {
      int gm = m0 + wr * 64 + mm * 16 + lhi * 4;
#pragma unroll
      for (int nn = 0; nn < 4; ++nn) {
        int gn = n0 + wc * 64 + nn * 16 + l15;
        float bv = bias[gn];
#pragma unroll
        for (int r = 0; r < 4; ++r)
          Cf[(size_t)(gm + r) * N + gn] = acc[mm][nn][r] + bv;
      }
    }
  }
}

// ---------------- flash attention: QBLK=128, KVBLK=64, LDS-staged K/V, swapped QK^T ----------------
__global__ __launch_bounds__(256) void attn_kernel(
    const unsigned short* __restrict__ qh, const unsigned short* __restrict__ kh,
    const unsigned short* __restrict__ vt, unsigned short* __restrict__ aout) {
  __shared__ unsigned short KT[2][4096];  // [kv 64][d 64] swizzled, 8KB/buf
  __shared__ unsigned short VT[2][4096];  // [d 64][kv 64] swizzled, 8KB/buf
  __shared__ unsigned short P[4][2048];   // per-wave 32x64 bf16
  __shared__ float Al[4][32];             // per-wave alpha[q] (rescale)
  __shared__ float Li[4][32];             // per-wave lrun[q] (final norm)

  const int tid = threadIdx.x, lane = tid & 63, wave = tid >> 6;
  const int l15 = lane & 15, lhi = lane >> 4;
  // XCD-locality decode: all 8 q-tiles of one bh -> same XCD (96 % 8 == 0), and
  // with 768 blocks all co-resident they co-run -> K/V L2-shared per XCD.
  const int bh = blockIdx.x % 96, qt = blockIdx.x / 96;
  const int b = bh / 12, h = bh % 12;
  const float c1 = 0.125f * 1.44269504088896340736f;  // scale * log2(e)

  // staging: thread t -> tile row = t>>3 (and +32), 16B chunk = t&7, inverse-swizzled src col
  const int srow = tid >> 3;
  const int scol = (((tid & 7) * 16) ^ ((srow & 7) << 4)) >> 1;
  const unsigned short* kS0 = kh + ((size_t)bh * 1024 + srow) * 64 + scol;
  const unsigned short* kS1 = kS0 + (size_t)32 * 64;
  const unsigned short* vS0 = vt + ((size_t)bh * 64 + srow) * 1024 + scol;
  const unsigned short* vS1 = vS0 + (size_t)32 * 1024;
  char* kD = (char*)&KT[0][0] + wave * 1024;
  char* vD = (char*)&VT[0][0] + wave * 1024;

  // Q fragments: 32 rows per wave (q = q0w + rb*16 + l15, d = ks*32 + lhi*8 + j)
  const int qw0 = qt * 128 + wave * 32;
  bf16x8 qf[2][2];
#pragma unroll
  for (int rb = 0; rb < 2; ++rb)
#pragma unroll
    for (int ks = 0; ks < 2; ++ks)
      qf[rb][ks] = *reinterpret_cast<const bf16x8*>(
          qh + ((size_t)bh * 1024 + qw0 + rb * 16 + l15) * 64 + ks * 32 + lhi * 8);

  f32x4 oacc[2][4] = {};
  float mrun[2] = {-1e30f, -1e30f}, lrun[2] = {0.f, 0.f};

  const int rswz = (l15 & 7) << 4;
  const int fo0 = l15 * 128 + ((lhi * 16) ^ rswz);
  const int fo1 = l15 * 128 + ((64 + lhi * 16) ^ rswz);
  unsigned short* pl = &P[wave][0];

  // prologue: stage tile 0 into buf 0
  gload16(kS0, kD); gload16(kS1, kD + 4096);
  gload16(vS0, vD); gload16(vS1, vD + 4096);

  for (int kt = 0; kt < 16; ++kt) {
    const int cur = kt & 1;
    if (kt < 15) {  // prefetch next tile into other buffer
      const int kv = (kt + 1) * 64;
      char* kd = kD + (cur ^ 1) * 8192;
      char* vd = vD + (cur ^ 1) * 8192;
      gload16(kS0 + (size_t)kv * 64, kd); gload16(kS1 + (size_t)kv * 64, kd + 4096);
      gload16(vS0 + kv, vd); gload16(vS1 + kv, vd + 4096);
      asm volatile("s_waitcnt vmcnt(4)" ::: "memory");
    } else {
      asm volatile("s_waitcnt vmcnt(0)" ::: "memory");
    }
    __builtin_amdgcn_s_barrier();

    const char* kb = (const char*)&KT[cur][0];
    const char* vb = (const char*)&VT[cur][0];

    // QK^T swapped: s[rb][nt] = D[kv = nt*16 + lhi*4 + r][q = rb*16 + l15]
    f32x4 s[2][4] = {};
#pragma unroll
    for (int nt = 0; nt < 4; ++nt) {
      bf16x8 kf0 = *reinterpret_cast<const bf16x8*>(kb + nt * 2048 + fo0);
      bf16x8 kf1 = *reinterpret_cast<const bf16x8*>(kb + nt * 2048 + fo1);
#pragma unroll
      for (int rb = 0; rb < 2; ++rb) {
        s[rb][nt] = __builtin_amdgcn_mfma_f32_16x16x32_bf16(kf0, qf[rb][0], s[rb][nt], 0, 0, 0);
        s[rb][nt] = __builtin_amdgcn_mfma_f32_16x16x32_bf16(kf1, qf[rb][1], s[rb][nt], 0, 0, 0);
      }
    }

    // ---- softmax: per-lane column q -> local tree + 2 shuffles ----
    float mt[2];
#pragma unroll
    for (int rb = 0; rb < 2; ++rb) {
      float a0 = fmaxf(fmaxf(s[rb][0][0], s[rb][0][1]), fmaxf(s[rb][0][2], s[rb][0][3]));
      float a1 = fmaxf(fmaxf(s[rb][1][0], s[rb][1][1]), fmaxf(s[rb][1][2], s[rb][1][3]));
      float a2 = fmaxf(fmaxf(s[rb][2][0], s[rb][2][1]), fmaxf(s[rb][2][2], s[rb][2][3]));
      float a3 = fmaxf(fmaxf(s[rb][3][0], s[rb][3][1]), fmaxf(s[rb][3][2], s[rb][3][3]));
      float rm = fmaxf(fmaxf(a0, a1), fmaxf(a2, a3));
      rm = fmaxf(rm, __shfl_xor(rm, 16, 64));
      rm = fmaxf(rm, __shfl_xor(rm, 32, 64));
      mt[rb] = rm * c1;
    }

    // T13 defer-max: rescale only when some q's max grew by >8 (log2 domain)
    bool ok = (mt[0] - mrun[0] <= 8.f) && (mt[1] - mrun[1] <= 8.f);
    if (!__all(ok)) {
      float al[2];
#pragma unroll
      for (int rb = 0; rb < 2; ++rb) {
        float mn = fmaxf(mrun[rb], mt[rb]);
        al[rb] = __builtin_amdgcn_exp2f(mrun[rb] - mn);
        mrun[rb] = mn;
        lrun[rb] *= al[rb];
      }
      if (lhi == 0) { Al[wave][l15] = al[0]; Al[wave][16 + l15] = al[1]; }
#pragma unroll
      for (int rb = 0; rb < 2; ++rb) {
        f32x4 av = *reinterpret_cast<const f32x4*>(&Al[wave][rb * 16 + lhi * 4]);
#pragma unroll
        for (int dt = 0; dt < 4; ++dt)
#pragma unroll
          for (int r = 0; r < 4; ++r) oacc[rb][dt][r] *= av[r];
      }
    }

#pragma unroll
    for (int rb = 0; rb < 2; ++rb) {
#pragma unroll
      for (int nt = 0; nt < 4; ++nt)
#pragma unroll
        for (int r = 0; r < 4; ++r)
          s[rb][nt][r] = __builtin_amdgcn_exp2f(__builtin_fmaf(s[rb][nt][r], c1, -mrun[rb]));

      float b0 = (s[rb][0][0] + s[rb][0][1]) + (s[rb][0][2] + s[rb][0][3]);
      float b1 = (s[rb][1][0] + s[rb][1][1]) + (s[rb][1][2] + s[rb][1][3]);
      float b2 = (s[rb][2][0] + s[rb][2][1]) + (s[rb][2][2] + s[rb][2][3]);
      float b3 = (s[rb][3][0] + s[rb][3][1]) + (s[rb][3][2] + s[rb][3][3]);
      float rs = (b0 + b1) + (b2 + b3);
      rs += __shfl_xor(rs, 16, 64);
      rs += __shfl_xor(rs, 32, 64);
      lrun[rb] += rs;
    }

    // ---- P -> swizzled LDS, packed b64 writes via v_cvt_pk_bf16_f32 ----
#pragma unroll
    for (int rb = 0; rb < 2; ++rb)
#pragma unroll
      for (int nt = 0; nt < 4; ++nt) {
        uint2 wv;
        wv.x = cvtpk(s[rb][nt][0], s[rb][nt][1]);
        wv.y = cvtpk(s[rb][nt][2], s[rb][nt][3]);
        *reinterpret_cast<uint2*>(
            (char*)pl + rb * 2048 + l15 * 128 + ((nt * 32 + lhi * 8) ^ rswz)) = wv;
      }

    bf16x8 paf[2][2];
#pragma unroll
    for (int rb = 0; rb < 2; ++rb) {
      paf[rb][0] = *reinterpret_cast<const bf16x8*>((char*)pl + rb * 2048 + fo0);
      paf[rb][1] = *reinterpret_cast<const bf16x8*>((char*)pl + rb * 2048 + fo1);
    }

#pragma unroll
    for (int dt = 0; dt < 4; ++dt) {
      bf16x8 vf0 = *reinterpret_cast<const bf16x8*>(vb + dt * 2048 + fo0);
      bf16x8 vf1 = *reinterpret_cast<const bf16x8*>(vb + dt * 2048 + fo1);
#pragma unroll
      for (int rb = 0; rb < 2; ++rb) {
        oacc[rb][dt] = __builtin_amdgcn_mfma_f32_16x16x32_bf16(paf[rb][0], vf0, oacc[rb][dt], 0, 0, 0);
        oacc[rb][dt] = __builtin_amdgcn_mfma_f32_16x16x32_bf16(paf[rb][1], vf1, oacc[rb][dt], 0, 0, 0);
      }
    }
    __builtin_amdgcn_s_barrier();
  }

  // ---- final normalize: redistribute lrun (per q=l15) to oacc rows (q=lhi*4+r) ----
  if (lhi == 0) { Li[wave][l15] = lrun[0]; Li[wave][16 + l15] = lrun[1]; }
#pragma unroll
  for (int rb = 0; rb < 2; ++rb) {
    f32x4 lv = *reinterpret_cast<const f32x4*>(&Li[wave][rb * 16 + lhi * 4]);
    float inv[4];
#pragma unroll
    for (int r = 0; r < 4; ++r) inv[r] = 1.f / lv[r];
#pragma unroll
    for (int dt = 0; dt < 4; ++dt)
#pragma unroll
      for (int r = 0; r < 4; ++r) {
        int n = qw0 + rb * 16 + lhi * 4 + r;
        int d = dt * 16 + l15;
        aout[((size_t)(b * 1024 + n)) * 768 + h * 64 + d] = f2bf(oacc[rb][dt][r] * inv[r]);
      }
  }
}

extern "C" void kernel_launch(void* const* d_in, const int* in_sizes, int n_in,
                              void* d_out, int out_size, void* d_ws, size_t ws_size,
                              hipStream_t stream) {
  const float* x      = (const float*)d_in[0];
  const float* qkv_w  = (const float*)d_in[1];
  const float* proj_w = (const float*)d_in[2];
  const float* proj_b = (const float*)d_in[3];
  float* out = (float*)d_out;

  char* ws = (char*)d_ws;
  unsigned short* xb     = (unsigned short*)(ws);              // 8192x768 bf16
  unsigned short* wqkvb  = (unsigned short*)(ws + 12582912);   // 2304x768
  unsigned short* wprojb = (unsigned short*)(ws + 16121856);   // 768x768
  unsigned short* qhb    = (unsigned short*)(ws + 17301504);   // [96][1024][64]
  unsigned short* khb    = (unsigned short*)(ws + 29884416);   // [96][1024][64]
  unsigned short* vtb    = (unsigned short*)(ws + 42467328);   // [96][64][1024]
  unsigned short* aob    = (unsigned short*)(ws + 55050240);   // 8192x768

  cast_kernel<<<6144, 256, 0, stream>>>(x, xb, 1572864);
  cast_kernel<<<1728, 256, 0, stream>>>(qkv_w, wqkvb, 442368);
  cast_kernel<<<576, 256, 0, stream>>>(proj_w, wprojb, 147456);

  dim3 g1(2304 / 128, 8192 / 128);
  gemm128<0><<<g1, 256, 0, stream>>>(xb, wqkvb, 768, 2304, qhb, khb, vtb, nullptr, nullptr);

  attn_kernel<<<96 * 8, 256, 0, stream>>>(qhb, khb, vtb, aob);

  dim3 g2(768 / 128, 8192 / 128);
  gemm128<1><<<g2, 256, 0, stream>>>(aob, wprojb, 768, 768, nullptr, nullptr, nullptr, out, proj_b);
}